// Round 3
// baseline (1080.728 us; speedup 1.0000x reference)
//
#include <hip/hip_runtime.h>
#include <hip/hip_bf16.h>

#define B_   256
#define T_   512
#define H_   128
#define G3_  384

// ---- tiled GEMM config ----
#define TM   128
#define TN   128
#define TK   32
#define LDA  132

typedef float v4f __attribute__((ext_vector_type(4)));

__device__ __forceinline__ float sigmoid_f(float x) {
    return 1.0f / (1.0f + __expf(-x));
}
__device__ __forceinline__ float tanh_f(float x) {
    return 1.0f - 2.0f / (__expf(2.0f * x) + 1.0f);
}

// Butterfly sum over each aligned 4-lane quad, pure DPP, result on ALL lanes.
__device__ __forceinline__ float bfly_fold4(float v) {
    int x;
    x = __builtin_amdgcn_update_dpp(0, __float_as_int(v), 0x0B1, 0xF, 0xF, true);
    v += __int_as_float(x);   // xor 1
    x = __builtin_amdgcn_update_dpp(0, __float_as_int(v), 0x04E, 0xF, 0xF, true);
    v += __int_as_float(x);   // xor 2
    return v;
}

#define DOT4(acc, hv, wv)                                        \
    acc = fmaf((hv).x, (wv).x, acc);                             \
    acc = fmaf((hv).y, (wv).y, acc);                             \
    acc = fmaf((hv).z, (wv).z, acc);                             \
    acc = fmaf((hv).w, (wv).w, acc);

// ---------------------------------------------------------------------------
// gx GEMM (unchanged from R2 — ~140 us, healthy)
// ---------------------------------------------------------------------------
template<bool GATHER>
__global__ __launch_bounds__(256, 2)
void gx_gemm(const float* __restrict__ X,
             const int*   __restrict__ idx,
             const float* __restrict__ emb,
             const float* __restrict__ W,     // [384,128] row-major
             const float* __restrict__ bias,  // [384]
             float*       __restrict__ gx)    // [M,384]
{
    __shared__ __align__(16) float As[2][TK][LDA];
    __shared__ __align__(16) float Bs[2][TK][LDA];

    const int tid = threadIdx.x;
    const int tn  = tid & 15;
    const int tm  = tid >> 4;
    const int n0  = blockIdx.x * TN;
    const int m0  = blockIdx.y * TM;

    const int q  = tid & 7;
    const float* rowA[4];
    const float* rowB[4];
#pragma unroll
    for (int s = 0; s < 4; s++) {
        const int r = (tid >> 3) + 32 * s;
        rowA[s] = GATHER ? (emb + (size_t)idx[m0 + r] * H_)
                         : (X + (size_t)(m0 + r) * H_);
        rowB[s] = W + (size_t)(n0 + r) * H_;
    }

    float4 stA[4], stB[4];
    auto load_chunk = [&](int kc) {
#pragma unroll
        for (int s = 0; s < 4; s++) {
            stA[s] = *(const float4*)(rowA[s] + kc + q * 4);
            stB[s] = *(const float4*)(rowB[s] + kc + q * 4);
        }
    };
    auto store_chunk = [&](int buf) {
#pragma unroll
        for (int s = 0; s < 4; s++) {
            const int r = (tid >> 3) + 32 * s;
#pragma unroll
            for (int d = 0; d < 4; d++) {
                As[buf][q * 4 + d][r] = ((const float*)&stA[s])[d];
                Bs[buf][q * 4 + d][r] = ((const float*)&stB[s])[d];
            }
        }
    };

    float4 acc[2][2][4];
#pragma unroll
    for (int a = 0; a < 2; a++)
#pragma unroll
        for (int b = 0; b < 2; b++)
#pragma unroll
            for (int c = 0; c < 4; c++) acc[a][b][c] = make_float4(0.f, 0.f, 0.f, 0.f);

    load_chunk(0);
    store_chunk(0);
    __syncthreads();

    for (int c = 0; c < 4; c++) {
        if (c < 3) load_chunk((c + 1) * TK);
        const int buf = c & 1;
#pragma unroll 4
        for (int k = 0; k < TK; k++) {
            float4 a0 = *(const float4*)&As[buf][k][tm * 4];
            float4 a1 = *(const float4*)&As[buf][k][64 + tm * 4];
            float4 b0 = *(const float4*)&Bs[buf][k][tn * 4];
            float4 b1 = *(const float4*)&Bs[buf][k][64 + tn * 4];
            float4 av[2] = {a0, a1}, bv[2] = {b0, b1};
#pragma unroll
            for (int mg = 0; mg < 2; mg++)
#pragma unroll
                for (int mi = 0; mi < 4; mi++) {
                    const float am = ((const float*)&av[mg])[mi];
#pragma unroll
                    for (int ng = 0; ng < 2; ng++) {
                        acc[mg][ng][mi].x = fmaf(am, bv[ng].x, acc[mg][ng][mi].x);
                        acc[mg][ng][mi].y = fmaf(am, bv[ng].y, acc[mg][ng][mi].y);
                        acc[mg][ng][mi].z = fmaf(am, bv[ng].z, acc[mg][ng][mi].z);
                        acc[mg][ng][mi].w = fmaf(am, bv[ng].w, acc[mg][ng][mi].w);
                    }
                }
        }
        if (c < 3) {
            store_chunk(buf ^ 1);
            __syncthreads();
        }
    }

    const float4 bb0 = *(const float4*)(bias + n0 + tn * 4);
    const float4 bb1 = *(const float4*)(bias + n0 + 64 + tn * 4);
#pragma unroll
    for (int mg = 0; mg < 2; mg++)
#pragma unroll
        for (int mi = 0; mi < 4; mi++) {
            const int m = m0 + mg * 64 + tm * 4 + mi;
            float* dst = gx + (size_t)m * G3_ + n0;
            float4 v0 = acc[mg][0][mi];
            v0.x += bb0.x; v0.y += bb0.y; v0.z += bb0.z; v0.w += bb0.w;
            float4 v1 = acc[mg][1][mi];
            v1.x += bb1.x; v1.y += bb1.y; v1.z += bb1.z; v1.w += bb1.w;
            *(float4*)(dst + tn * 4) = v0;
            *(float4*)(dst + 64 + tn * 4) = v1;
        }
}

// ---------------------------------------------------------------------------
// GRU recurrence — R10 gate-ownership structure + R11 register fix.
//
// 512 threads/block, one block per batch row. Thread (jg = tid>>2, ks = tid&3)
// owns HIDDEN UNIT jg: W_hh rows jg (r), jg+128 (z), jg+256 (n), cols
// ks*32..+31 (96 floats that must be ARCH-VGPR resident).
//
// R11: __launch_bounds__' 2nd arg sets only the MIN waves/EU — the backend
// occupancy heuristic still targeted 8 waves/EU (64-VGPR budget), pushing W
// into AGPRs (VGPR_Count=64, VALU issue ~1400 cyc/step vs ~570 counted =
// per-use v_accvgpr_read copies). amdgpu_waves_per_eu(2,2) pins the MAX to
// the physically-achieved occupancy (grid = 1 block/CU = 2 waves/EU), fixing
// the allocator budget at 256 VGPRs -> W + live set (~160) fits cleanly.
// Also: prefetch/store pointers are strength-reduced (gnx += G3_, hp += H_);
// the old min(t+1) clamp is gone — the final prefetch reads one row past,
// which is mapped (h1 follows gx in the workspace) and discarded.
// ---------------------------------------------------------------------------
template<bool STORE_H, bool FINAL>
__global__ __launch_bounds__(512)
__attribute__((amdgpu_waves_per_eu(2, 2)))
void gru_rec(const float* __restrict__ gx,   // [B,T,384]
             const float* __restrict__ Whh,  // [384,128]
             const float* __restrict__ bhh,  // [384]
             float*       __restrict__ hseq, // [B,T,128] if STORE_H
             const float* __restrict__ fc_w, // [3,128]  if FINAL
             const float* __restrict__ fc_b, // [3]      if FINAL
             float*       __restrict__ out)  // [B,3]    if FINAL
{
    __shared__ __align__(16) float h2[2][H_];   // double-buffered swizzled h

    const int tid = threadIdx.x;
    const int b   = blockIdx.x;
    const int jg  = tid >> 2;      // hidden unit 0..127
    const int ks  = tid & 3;       // k-slice 0..3 (32 cols each)

    // --- W_hh fragment: rows jg / jg+128 / jg+256, cols ks*32..+31 ---
    const v4f* wr = (const v4f*)(Whh + (size_t)(jg      ) * H_ + ks * 32);
    const v4f* wz = (const v4f*)(Whh + (size_t)(jg + 128) * H_ + ks * 32);
    const v4f* wn = (const v4f*)(Whh + (size_t)(jg + 256) * H_ + ks * 32);
    v4f Wr[8], Wz[8], Wn[8];
#pragma unroll
    for (int c = 0; c < 8; c++) { Wr[c] = wr[c]; Wz[c] = wz[c]; Wn[c] = wn[c]; }

    const float bhr = bhh[jg];
    const float bhz = bhh[jg + 128];
    const float bhn = bhh[jg + 256];

    const float* gxb = gx + (size_t)b * T_ * G3_;
    float gr = gxb[jg], gz = gxb[jg + 128], gn = gxb[jg + 256];
    float h_old = 0.0f;

    if (tid < H_) h2[0][tid] = 0.0f;   // zeros are swizzle-invariant

    // write word for this unit: sw(jg)
    const int hw = ((jg >> 2) & 7) * 16 + (jg >> 5) * 4 + (jg & 3);
    const int hb = ks * 4;             // read base within each 16-word chunk

    // walked pointers (strength-reduced; no per-step mul / clamp)
    const float* gnx = gxb + G3_;
    float* hp = STORE_H ? (hseq + (size_t)b * T_ * H_ + jg) : nullptr;

    __syncthreads();

    // keep the W fragment register-resident (cannot be re-sunk into the loop)
#pragma unroll
    for (int c = 0; c < 8; c++) {
        asm volatile("" : "+v"(Wr[c]), "+v"(Wz[c]), "+v"(Wn[c]));
    }

#define GRU_STEP(HIN, HOUT)                                                   \
    {                                                                         \
        const float gr2_ = gnx[jg];                                           \
        const float gz2_ = gnx[jg + 128];                                     \
        const float gn2_ = gnx[jg + 256];                                     \
        gnx += G3_;                                                           \
        float p0 = 0.f, p1 = 0.f, p2 = 0.f;                                   \
        _Pragma("unroll")                                                     \
        for (int c = 0; c < 8; c++) {                                         \
            float4 hv = *(const float4*)&(HIN)[16 * c + hb];                  \
            DOT4(p0, hv, Wr[c]) DOT4(p1, hv, Wz[c]) DOT4(p2, hv, Wn[c])      \
        }                                                                     \
        p0 = bfly_fold4(p0);                                                  \
        p1 = bfly_fold4(p1);                                                  \
        p2 = bfly_fold4(p2);                                                  \
        const float r_ = sigmoid_f(gr + p0 + bhr);                            \
        const float z_ = sigmoid_f(gz + p1 + bhz);                            \
        const float n_ = tanh_f(gn + r_ * (p2 + bhn));                        \
        h_old = (1.0f - z_) * n_ + z_ * h_old;                                \
        if (ks == 0) {                                                        \
            (HOUT)[hw] = h_old;                                               \
            if (STORE_H) *hp = h_old;                                         \
        }                                                                     \
        if (STORE_H) hp += H_;                                                \
        gr = gr2_; gz = gz2_; gn = gn2_;                                      \
        __syncthreads();                                                      \
    }

    for (int t = 0; t < T_; t += 2) {
        GRU_STEP(h2[0], h2[1])
        GRU_STEP(h2[1], h2[0])
    }
#undef GRU_STEP

    if (FINAL) {
        // h2[1] is dead after the loop's trailing barrier — reuse linearly.
        if (ks == 0) h2[1][jg] = fmaxf(h_old, 0.0f);   // relu(last hidden)
        __syncthreads();
        if (tid < 3) {
            float acc = fc_b[tid];
            const float* fw = fc_w + tid * H_;
#pragma unroll
            for (int k = 0; k < H_; k++) acc = fmaf(h2[1][k], fw[k], acc);
            out[b * 3 + tid] = acc;
        }
    }
}

// ---------------------------------------------------------------------------
extern "C" void kernel_launch(void* const* d_in, const int* in_sizes, int n_in,
                              void* d_out, int out_size, void* d_ws, size_t ws_size,
                              hipStream_t stream)
{
    const int*   x    = (const int*)  d_in[0];
    const float* emb  = (const float*)d_in[1];
    const float* W_ih = (const float*)d_in[2];  // [2,384,128]
    const float* W_hh = (const float*)d_in[3];  // [2,384,128]
    const float* b_ih = (const float*)d_in[4];  // [2,384]
    const float* b_hh = (const float*)d_in[5];  // [2,384]
    const float* fc_w = (const float*)d_in[6];  // [3,128]
    const float* fc_b = (const float*)d_in[7];  // [3]
    float* out = (float*)d_out;

    const int M = B_ * T_;                                   // 131072 rows
    const size_t gx_f32 = (size_t)M * G3_ * sizeof(float);   // 201.3 MB

    float* gx = (float*)d_ws;
    float* h1 = (float*)((char*)d_ws + gx_f32);              // 67.1 MB

    dim3 ggx(G3_ / TN, M / TM);   // (3, 1024)
    dim3 bgx(256);
    dim3 grec(B_), brec(512);

    hipLaunchKernelGGL((gx_gemm<true>), ggx, bgx, 0, stream,
                       nullptr, x, emb, W_ih, b_ih, gx);
    hipLaunchKernelGGL((gru_rec<true, false>), grec, brec, 0, stream,
                       gx, W_hh, b_hh, h1, nullptr, nullptr, nullptr);
    hipLaunchKernelGGL((gx_gemm<false>), ggx, bgx, 0, stream,
                       h1, nullptr, nullptr, W_ih + G3_ * H_, b_ih + G3_, gx);
    hipLaunchKernelGGL((gru_rec<false, true>), grec, brec, 0, stream,
                       gx, W_hh + G3_ * H_, b_hh + G3_, nullptr, fc_w, fc_b, out);
}

// Round 4
// 935.785 us; speedup vs baseline: 1.1549x; 1.1549x over previous
//
#include <hip/hip_runtime.h>
#include <hip/hip_bf16.h>

#define B_   256
#define T_   512
#define H_   128
#define G3_  384

// ---- tiled GEMM config ----
#define TM   128
#define TN   128
#define TK   32
#define LDA  132

typedef float v4f __attribute__((ext_vector_type(4)));

// Raw v_rcp_f32 (~1 ulp) — avoids the IEEE v_div_scale/fmas/fixup sequence
// (~10 VALU + ~30cyc latency per divide) that non-fast-math 1/x emits.
__device__ __forceinline__ float fast_rcp(float x) {
    return __builtin_amdgcn_rcpf(x);
}
__device__ __forceinline__ float sigmoid_f(float x) {
    return fast_rcp(1.0f + __expf(-x));
}
__device__ __forceinline__ float tanh_f(float x) {
    return fmaf(-2.0f, fast_rcp(__expf(2.0f * x) + 1.0f), 1.0f);
}

// Butterfly sum over each aligned 4-lane quad, pure DPP, result on ALL lanes.
__device__ __forceinline__ float bfly_fold4(float v) {
    int x;
    x = __builtin_amdgcn_update_dpp(0, __float_as_int(v), 0x0B1, 0xF, 0xF, true);
    v += __int_as_float(x);   // xor 1
    x = __builtin_amdgcn_update_dpp(0, __float_as_int(v), 0x04E, 0xF, 0xF, true);
    v += __int_as_float(x);   // xor 2
    return v;
}

#define DOT4(acc, hv, wv)                                        \
    acc = fmaf((hv).x, (wv).x, acc);                             \
    acc = fmaf((hv).y, (wv).y, acc);                             \
    acc = fmaf((hv).z, (wv).z, acc);                             \
    acc = fmaf((hv).w, (wv).w, acc);

// ---------------------------------------------------------------------------
// gx GEMM (unchanged from R2 — ~140 us, healthy)
// ---------------------------------------------------------------------------
template<bool GATHER>
__global__ __launch_bounds__(256, 2)
void gx_gemm(const float* __restrict__ X,
             const int*   __restrict__ idx,
             const float* __restrict__ emb,
             const float* __restrict__ W,     // [384,128] row-major
             const float* __restrict__ bias,  // [384]
             float*       __restrict__ gx)    // [M,384]
{
    __shared__ __align__(16) float As[2][TK][LDA];
    __shared__ __align__(16) float Bs[2][TK][LDA];

    const int tid = threadIdx.x;
    const int tn  = tid & 15;
    const int tm  = tid >> 4;
    const int n0  = blockIdx.x * TN;
    const int m0  = blockIdx.y * TM;

    const int q  = tid & 7;
    const float* rowA[4];
    const float* rowB[4];
#pragma unroll
    for (int s = 0; s < 4; s++) {
        const int r = (tid >> 3) + 32 * s;
        rowA[s] = GATHER ? (emb + (size_t)idx[m0 + r] * H_)
                         : (X + (size_t)(m0 + r) * H_);
        rowB[s] = W + (size_t)(n0 + r) * H_;
    }

    float4 stA[4], stB[4];
    auto load_chunk = [&](int kc) {
#pragma unroll
        for (int s = 0; s < 4; s++) {
            stA[s] = *(const float4*)(rowA[s] + kc + q * 4);
            stB[s] = *(const float4*)(rowB[s] + kc + q * 4);
        }
    };
    auto store_chunk = [&](int buf) {
#pragma unroll
        for (int s = 0; s < 4; s++) {
            const int r = (tid >> 3) + 32 * s;
#pragma unroll
            for (int d = 0; d < 4; d++) {
                As[buf][q * 4 + d][r] = ((const float*)&stA[s])[d];
                Bs[buf][q * 4 + d][r] = ((const float*)&stB[s])[d];
            }
        }
    };

    float4 acc[2][2][4];
#pragma unroll
    for (int a = 0; a < 2; a++)
#pragma unroll
        for (int b = 0; b < 2; b++)
#pragma unroll
            for (int c = 0; c < 4; c++) acc[a][b][c] = make_float4(0.f, 0.f, 0.f, 0.f);

    load_chunk(0);
    store_chunk(0);
    __syncthreads();

    for (int c = 0; c < 4; c++) {
        if (c < 3) load_chunk((c + 1) * TK);
        const int buf = c & 1;
#pragma unroll 4
        for (int k = 0; k < TK; k++) {
            float4 a0 = *(const float4*)&As[buf][k][tm * 4];
            float4 a1 = *(const float4*)&As[buf][k][64 + tm * 4];
            float4 b0 = *(const float4*)&Bs[buf][k][tn * 4];
            float4 b1 = *(const float4*)&Bs[buf][k][64 + tn * 4];
            float4 av[2] = {a0, a1}, bv[2] = {b0, b1};
#pragma unroll
            for (int mg = 0; mg < 2; mg++)
#pragma unroll
                for (int mi = 0; mi < 4; mi++) {
                    const float am = ((const float*)&av[mg])[mi];
#pragma unroll
                    for (int ng = 0; ng < 2; ng++) {
                        acc[mg][ng][mi].x = fmaf(am, bv[ng].x, acc[mg][ng][mi].x);
                        acc[mg][ng][mi].y = fmaf(am, bv[ng].y, acc[mg][ng][mi].y);
                        acc[mg][ng][mi].z = fmaf(am, bv[ng].z, acc[mg][ng][mi].z);
                        acc[mg][ng][mi].w = fmaf(am, bv[ng].w, acc[mg][ng][mi].w);
                    }
                }
        }
        if (c < 3) {
            store_chunk(buf ^ 1);
            __syncthreads();
        }
    }

    const float4 bb0 = *(const float4*)(bias + n0 + tn * 4);
    const float4 bb1 = *(const float4*)(bias + n0 + 64 + tn * 4);
#pragma unroll
    for (int mg = 0; mg < 2; mg++)
#pragma unroll
        for (int mi = 0; mi < 4; mi++) {
            const int m = m0 + mg * 64 + tm * 4 + mi;
            float* dst = gx + (size_t)m * G3_ + n0;
            float4 v0 = acc[mg][0][mi];
            v0.x += bb0.x; v0.y += bb0.y; v0.z += bb0.z; v0.w += bb0.w;
            float4 v1 = acc[mg][1][mi];
            v1.x += bb1.x; v1.y += bb1.y; v1.z += bb1.z; v1.w += bb1.w;
            *(float4*)(dst + tn * 4) = v0;
            *(float4*)(dst + 64 + tn * 4) = v1;
        }
}

// ---------------------------------------------------------------------------
// GRU recurrence — R10 gate-ownership structure.
//
// 512 threads/block, one block per batch row. Thread (jg = tid>>2, ks = tid&3)
// owns HIDDEN UNIT jg: W_hh rows jg (r), jg+128 (z), jg+256 (n), cols
// ks*32..+31 (96 floats that must be ARCH-VGPR resident).
//
// R12: (a) the W pin moves INSIDE the T-loop — R11's pre-loop pin constrained
// only one program point, and the allocator demoted W to AGPRs for the loop
// body (VGPR_Count=88: live set + ~half W; per-use v_accvgpr_read copies ~=
// the ~200 unexplained VALU ops/thread/step). An empty in-loop asm with
// "+v" on all 24 v4f forces arch-VGPR residency every iteration at zero
// instruction cost. (b) sigmoid/tanh use raw v_rcp_f32 instead of IEEE
// divides (3 div sequences ~10 VALU + ~30cyc latency each, on the serial
// inter-step critical path).
// ---------------------------------------------------------------------------
template<bool STORE_H, bool FINAL>
__global__ __launch_bounds__(512)
__attribute__((amdgpu_waves_per_eu(2, 2)))
void gru_rec(const float* __restrict__ gx,   // [B,T,384]
             const float* __restrict__ Whh,  // [384,128]
             const float* __restrict__ bhh,  // [384]
             float*       __restrict__ hseq, // [B,T,128] if STORE_H
             const float* __restrict__ fc_w, // [3,128]  if FINAL
             const float* __restrict__ fc_b, // [3]      if FINAL
             float*       __restrict__ out)  // [B,3]    if FINAL
{
    __shared__ __align__(16) float h2[2][H_];   // double-buffered swizzled h

    const int tid = threadIdx.x;
    const int b   = blockIdx.x;
    const int jg  = tid >> 2;      // hidden unit 0..127
    const int ks  = tid & 3;       // k-slice 0..3 (32 cols each)

    // --- W_hh fragment: rows jg / jg+128 / jg+256, cols ks*32..+31 ---
    const v4f* wr = (const v4f*)(Whh + (size_t)(jg      ) * H_ + ks * 32);
    const v4f* wz = (const v4f*)(Whh + (size_t)(jg + 128) * H_ + ks * 32);
    const v4f* wn = (const v4f*)(Whh + (size_t)(jg + 256) * H_ + ks * 32);
    v4f Wr[8], Wz[8], Wn[8];
#pragma unroll
    for (int c = 0; c < 8; c++) { Wr[c] = wr[c]; Wz[c] = wz[c]; Wn[c] = wn[c]; }

    const float bhr = bhh[jg];
    const float bhz = bhh[jg + 128];
    const float bhn = bhh[jg + 256];

    const float* gxb = gx + (size_t)b * T_ * G3_;
    float gr = gxb[jg], gz = gxb[jg + 128], gn = gxb[jg + 256];
    float h_old = 0.0f;

    if (tid < H_) h2[0][tid] = 0.0f;   // zeros are swizzle-invariant

    // write word for this unit: sw(jg)
    const int hw = ((jg >> 2) & 7) * 16 + (jg >> 5) * 4 + (jg & 3);
    const int hb = ks * 4;             // read base within each 16-word chunk

    // walked pointers (strength-reduced; no per-step mul / clamp)
    const float* gnx = gxb + G3_;
    float* hp = STORE_H ? (hseq + (size_t)b * T_ * H_ + jg) : nullptr;

    __syncthreads();

#define GRU_STEP(HIN, HOUT)                                                   \
    {                                                                         \
        const float gr2_ = gnx[jg];                                           \
        const float gz2_ = gnx[jg + 128];                                     \
        const float gn2_ = gnx[jg + 256];                                     \
        gnx += G3_;                                                           \
        float p0 = 0.f, p1 = 0.f, p2 = 0.f;                                   \
        _Pragma("unroll")                                                     \
        for (int c = 0; c < 8; c++) {                                         \
            float4 hv = *(const float4*)&(HIN)[16 * c + hb];                  \
            DOT4(p0, hv, Wr[c]) DOT4(p1, hv, Wz[c]) DOT4(p2, hv, Wn[c])      \
        }                                                                     \
        p0 = bfly_fold4(p0);                                                  \
        p1 = bfly_fold4(p1);                                                  \
        p2 = bfly_fold4(p2);                                                  \
        const float r_ = sigmoid_f(gr + p0 + bhr);                            \
        const float z_ = sigmoid_f(gz + p1 + bhz);                            \
        const float n_ = tanh_f(gn + r_ * (p2 + bhn));                        \
        h_old = (1.0f - z_) * n_ + z_ * h_old;                                \
        if (ks == 0) {                                                        \
            (HOUT)[hw] = h_old;                                               \
            if (STORE_H) *hp = h_old;                                         \
        }                                                                     \
        if (STORE_H) hp += H_;                                                \
        gr = gr2_; gz = gz2_; gn = gn2_;                                      \
        __syncthreads();                                                      \
    }

    for (int t = 0; t < T_; t += 2) {
        // In-loop arch-VGPR pin: zero instructions, but forces all 24 W
        // fragments to live in arch VGPRs at every iteration boundary so the
        // allocator cannot demote them to AGPRs (per-use v_accvgpr_read) or
        // per-step reloads. Budget is 256 VGPRs (waves_per_eu(2,2)).
        asm volatile("" : "+v"(Wr[0]), "+v"(Wr[1]), "+v"(Wr[2]), "+v"(Wr[3]),
                          "+v"(Wr[4]), "+v"(Wr[5]), "+v"(Wr[6]), "+v"(Wr[7]),
                          "+v"(Wz[0]), "+v"(Wz[1]), "+v"(Wz[2]), "+v"(Wz[3]),
                          "+v"(Wz[4]), "+v"(Wz[5]), "+v"(Wz[6]), "+v"(Wz[7]),
                          "+v"(Wn[0]), "+v"(Wn[1]), "+v"(Wn[2]), "+v"(Wn[3]),
                          "+v"(Wn[4]), "+v"(Wn[5]), "+v"(Wn[6]), "+v"(Wn[7]));
        GRU_STEP(h2[0], h2[1])
        GRU_STEP(h2[1], h2[0])
    }
#undef GRU_STEP

    if (FINAL) {
        // h2[1] is dead after the loop's trailing barrier — reuse linearly.
        if (ks == 0) h2[1][jg] = fmaxf(h_old, 0.0f);   // relu(last hidden)
        __syncthreads();
        if (tid < 3) {
            float acc = fc_b[tid];
            const float* fw = fc_w + tid * H_;
#pragma unroll
            for (int k = 0; k < H_; k++) acc = fmaf(h2[1][k], fw[k], acc);
            out[b * 3 + tid] = acc;
        }
    }
}

// ---------------------------------------------------------------------------
extern "C" void kernel_launch(void* const* d_in, const int* in_sizes, int n_in,
                              void* d_out, int out_size, void* d_ws, size_t ws_size,
                              hipStream_t stream)
{
    const int*   x    = (const int*)  d_in[0];
    const float* emb  = (const float*)d_in[1];
    const float* W_ih = (const float*)d_in[2];  // [2,384,128]
    const float* W_hh = (const float*)d_in[3];  // [2,384,128]
    const float* b_ih = (const float*)d_in[4];  // [2,384]
    const float* b_hh = (const float*)d_in[5];  // [2,384]
    const float* fc_w = (const float*)d_in[6];  // [3,128]
    const float* fc_b = (const float*)d_in[7];  // [3]
    float* out = (float*)d_out;

    const int M = B_ * T_;                                   // 131072 rows
    const size_t gx_f32 = (size_t)M * G3_ * sizeof(float);   // 201.3 MB

    float* gx = (float*)d_ws;
    float* h1 = (float*)((char*)d_ws + gx_f32);              // 67.1 MB

    dim3 ggx(G3_ / TN, M / TM);   // (3, 1024)
    dim3 bgx(256);
    dim3 grec(B_), brec(512);

    hipLaunchKernelGGL((gx_gemm<true>), ggx, bgx, 0, stream,
                       nullptr, x, emb, W_ih, b_ih, gx);
    hipLaunchKernelGGL((gru_rec<true, false>), grec, brec, 0, stream,
                       gx, W_hh, b_hh, h1, nullptr, nullptr, nullptr);
    hipLaunchKernelGGL((gx_gemm<false>), ggx, bgx, 0, stream,
                       h1, nullptr, nullptr, W_ih + G3_ * H_, b_ih + G3_, gx);
    hipLaunchKernelGGL((gru_rec<false, true>), grec, brec, 0, stream,
                       gx, W_hh + G3_ * H_, b_hh + G3_, nullptr, fc_w, fc_b, out);
}